// Round 4
// baseline (891.146 us; speedup 1.0000x reference)
//
#include <hip/hip_runtime.h>
#include <hip/hip_bf16.h>

// GraphSAGE 3-layer, N=50000 nodes, E=400000 edges, dims 512->512->512->128.
// Round 3 -> 4 changes (GEMM was latency-bound: MfmaUtil 10%, VALUBusy 12%,
// FETCH 229MB vs 103MB ideal):
//  - register-staged double-buffered K-loop: global_load->VGPR prefetch of
//    tile k+1 issued before computing tile k; plain loads are NOT drained at
//    s_barrier (unlike global_load_lds), so latency is truly hidden
//  - two passes fused into one K=1024 loop (pointer select per k-chunk)
//  - XCD swizzle: 4 col-tiles of one row-strip grouped to one XCD so the
//    shared A strip is fetched from HBM once, L2 thereafter

#define N_NODES 50000
#define N_EDGES 400000

typedef unsigned short u16;
typedef unsigned int u32;
typedef __attribute__((ext_vector_type(8))) short short8;
typedef __attribute__((ext_vector_type(4))) float floatx4;

__device__ __forceinline__ u16 f32_to_bf16(float f) {
    u32 u = __float_as_uint(f);
    u32 r = 0x7FFFu + ((u >> 16) & 1u);
    return (u16)((u + r) >> 16);
}
__device__ __forceinline__ float bf16_to_f32(u32 lo16) {
    return __uint_as_float(lo16 << 16);
}

__global__ __launch_bounds__(256) void zero4_kernel(float4* __restrict__ p, int n4) {
    int i = blockIdx.x * 256 + threadIdx.x;
    if (i < n4) p[i] = make_float4(0.f, 0.f, 0.f, 0.f);
}

__global__ __launch_bounds__(256) void hist_kernel(const int* __restrict__ dst,
                                                   int* __restrict__ deg, int E) {
    int e = blockIdx.x * 256 + threadIdx.x;
    if (e < E) atomicAdd(&deg[dst[e]], 1);
}

__global__ __launch_bounds__(256) void scan_reduce(const int* __restrict__ v,
                                                   int* __restrict__ bsums, int n) {
    __shared__ int sh[256];
    int i = blockIdx.x * 256 + threadIdx.x;
    sh[threadIdx.x] = (i < n) ? v[i] : 0;
    __syncthreads();
    for (int off = 128; off > 0; off >>= 1) {
        if (threadIdx.x < off) sh[threadIdx.x] += sh[threadIdx.x + off];
        __syncthreads();
    }
    if (threadIdx.x == 0) bsums[blockIdx.x] = sh[0];
}

__global__ __launch_bounds__(256) void scan_sums(int* __restrict__ bsums, int nb) {
    __shared__ int sh[256];
    int t = threadIdx.x;
    int val = (t < nb) ? bsums[t] : 0;
    sh[t] = val;
    __syncthreads();
    for (int off = 1; off < 256; off <<= 1) {
        int v = (t >= off) ? sh[t - off] : 0;
        __syncthreads();
        sh[t] += v;
        __syncthreads();
    }
    if (t < nb) bsums[t] = sh[t] - val;
}

__global__ __launch_bounds__(256) void scan_final(int* __restrict__ v,
                                                  const int* __restrict__ bsums, int n) {
    __shared__ int sh[256];
    int t = threadIdx.x;
    int i = blockIdx.x * 256 + t;
    int val = (i < n) ? v[i] : 0;
    sh[t] = val;
    __syncthreads();
    for (int off = 1; off < 256; off <<= 1) {
        int x = (t >= off) ? sh[t - off] : 0;
        __syncthreads();
        sh[t] += x;
        __syncthreads();
    }
    int excl = sh[t] - val + bsums[blockIdx.x];
    if (i < n) v[i] = excl;
    if (i == n - 1) v[n] = excl + val;
}

__global__ __launch_bounds__(256) void fill_kernel(const int* __restrict__ src,
                                                   const int* __restrict__ dst,
                                                   const int* __restrict__ row_start,
                                                   int* __restrict__ cursor,
                                                   int* __restrict__ csr_src, int E) {
    int e = blockIdx.x * 256 + threadIdx.x;
    if (e < E) {
        int d = dst[e];
        int pos = row_start[d] + atomicAdd(&cursor[d], 1);
        csr_src[pos] = src[e];
    }
}

// f32 [n8*8] -> bf16, 8 elems/thread
__global__ __launch_bounds__(256) void convert_bf16(const float* __restrict__ in,
                                                    u16* __restrict__ out, int n8) {
    int i = blockIdx.x * 256 + threadIdx.x;
    if (i >= n8) return;
    const float4* p = (const float4*)in + (size_t)i * 2;
    float4 v0 = p[0], v1 = p[1];
    uint4 o;
    o.x = (u32)f32_to_bf16(v0.x) | ((u32)f32_to_bf16(v0.y) << 16);
    o.y = (u32)f32_to_bf16(v0.z) | ((u32)f32_to_bf16(v0.w) << 16);
    o.z = (u32)f32_to_bf16(v1.x) | ((u32)f32_to_bf16(v1.y) << 16);
    o.w = (u32)f32_to_bf16(v1.z) | ((u32)f32_to_bf16(v1.w) << 16);
    ((uint4*)out)[i] = o;
}

// W [K][N] f32 -> WT [N][K] bf16, 32x32 tiles
__global__ __launch_bounds__(256) void transpose_w(const float* __restrict__ W,
                                                   u16* __restrict__ WT,
                                                   int K, int N) {
    __shared__ float t[32][33];
    int n0 = blockIdx.x * 32, k0 = blockIdx.y * 32;
    int c = threadIdx.x & 31, r0 = threadIdx.x >> 5;
    for (int r = r0; r < 32; r += 8)
        t[r][c] = W[(size_t)(k0 + r) * N + n0 + c];
    __syncthreads();
    for (int r = r0; r < 32; r += 8)
        WT[(size_t)(n0 + r) * K + k0 + c] = f32_to_bf16(t[c][r]);
}

// One wave per node: mean of neighbor bf16 rows, fp32 accum, bf16 out.
__global__ __launch_bounds__(256) void gather_mean_bf16(const u16* __restrict__ X,
                                                        const int* __restrict__ row_start,
                                                        const int* __restrict__ csr_src,
                                                        u16* __restrict__ agg, int M) {
    int node = (blockIdx.x * 256 + threadIdx.x) >> 6;
    int lane = threadIdx.x & 63;
    if (node >= M) return;
    int beg = row_start[node], end = row_start[node + 1];
    float a[8] = {0.f, 0.f, 0.f, 0.f, 0.f, 0.f, 0.f, 0.f};
    for (int c = beg; c < end; c += 64) {
        int nb = min(64, end - c);
        int eid = (lane < nb) ? csr_src[c + lane] : 0;
        for (int i = 0; i < nb; ++i) {
            int s = __shfl(eid, i);
            uint4 v = ((const uint4*)(X + (size_t)s * 512))[lane];
            a[0] += bf16_to_f32(v.x & 0xffffu); a[1] += bf16_to_f32(v.x >> 16);
            a[2] += bf16_to_f32(v.y & 0xffffu); a[3] += bf16_to_f32(v.y >> 16);
            a[4] += bf16_to_f32(v.z & 0xffffu); a[5] += bf16_to_f32(v.z >> 16);
            a[6] += bf16_to_f32(v.w & 0xffffu); a[7] += bf16_to_f32(v.w >> 16);
        }
    }
    float inv = 1.0f / fmaxf((float)(end - beg), 1.0f);
    uint4 o;
    o.x = (u32)f32_to_bf16(a[0] * inv) | ((u32)f32_to_bf16(a[1] * inv) << 16);
    o.y = (u32)f32_to_bf16(a[2] * inv) | ((u32)f32_to_bf16(a[3] * inv) << 16);
    o.z = (u32)f32_to_bf16(a[4] * inv) | ((u32)f32_to_bf16(a[5] * inv) << 16);
    o.w = (u32)f32_to_bf16(a[6] * inv) | ((u32)f32_to_bf16(a[7] * inv) << 16);
    ((uint4*)(agg + (size_t)node * 512))[lane] = o;
}

// C[M,N] = A1@B1T' + A2@B2T' + bias (B*T stored [N][512]), optional relu.
// 128x128 tile, fused K=1024 (pass select per 32-chunk), register-staged
// double-buffered LDS, XCD-swizzled 1D grid.
// nStrips = ceil(M/128); nCols = N/128. If nCols==4, grid must be
// ceil(nStrips/8)*32 with the group swizzle; if nCols==1, grid = nStrips.
__global__ __launch_bounds__(256) void gemm_bf16(
    const u16* __restrict__ A1, const u16* __restrict__ A2,
    const u16* __restrict__ B1T, const u16* __restrict__ B2T,
    const float* __restrict__ bias,
    u16* __restrict__ Cb, float* __restrict__ Cf,
    int M, int N, int relu, int nStrips, int nCols) {
    __shared__ u16 As[2][4096];  // [buf][kq*128 + row granules of 8 bf16]
    __shared__ u16 Bs[2][4096];

    int strip, colt;
    if (nCols == 4) {
        int b = blockIdx.x;
        int g = b >> 5, w5 = b & 31;
        strip = g * 8 + (w5 & 7);   // 4 col-tiles of a strip share b%8 -> same XCD
        colt = w5 >> 3;
        if (strip >= nStrips) return;
    } else {
        strip = blockIdx.x;
        colt = 0;
    }
    const int row0 = strip * 128, col0 = colt * 128;

    const int t = threadIdx.x;
    const int w = t >> 6, lane = t & 63;
    const int wm = (w >> 1) * 64, wn = (w & 1) * 64;
    const int l15 = lane & 15, kq = lane >> 4;

    floatx4 acc[4][4];
#pragma unroll
    for (int i = 0; i < 4; ++i)
#pragma unroll
        for (int j = 0; j < 4; ++j) acc[i][j] = floatx4{0.f, 0.f, 0.f, 0.f};

    // Per-thread staging addresses (K stride fixed 512). Wave w owns kq-chunk w.
    const size_t aoff0 = (size_t)min(row0 + lane, M - 1) * 512 + w * 8;
    const size_t aoff1 = (size_t)min(row0 + 64 + lane, M - 1) * 512 + w * 8;
    const size_t boff0 = (size_t)(col0 + lane) * 512 + w * 8;
    const size_t boff1 = (size_t)(col0 + 64 + lane) * 512 + w * 8;
    const int gA0 = (w * 128 + lane) * 8;        // LDS granule offsets (u16 idx)
    const int gA1 = (w * 128 + 64 + lane) * 8;

    uint4 ra0, ra1, rb0, rb1;
    auto loadTile = [&](int it) {
        int k0 = it * 32;
        const u16* Ap = (k0 < 512) ? A1 : A2;
        const u16* Bp = (k0 < 512) ? B1T : B2T;
        int eff = k0 & 511;
        ra0 = *(const uint4*)(Ap + aoff0 + eff);
        ra1 = *(const uint4*)(Ap + aoff1 + eff);
        rb0 = *(const uint4*)(Bp + boff0 + eff);
        rb1 = *(const uint4*)(Bp + boff1 + eff);
    };

    loadTile(0);
    for (int it = 0; it < 32; ++it) {
        const int buf = it & 1;
        __syncthreads();   // all waves done computing from this buffer (it-2)
        *(uint4*)&As[buf][gA0] = ra0;
        *(uint4*)&As[buf][gA1] = ra1;
        *(uint4*)&Bs[buf][gA0] = rb0;
        *(uint4*)&Bs[buf][gA1] = rb1;
        if (it + 1 < 32) loadTile(it + 1);  // prefetch: stays in flight across barrier
        __syncthreads();   // buffer visible

        const short8* Asv = (const short8*)&As[buf][0];
        const short8* Bsv = (const short8*)&Bs[buf][0];
        short8 a[4], b[4];
#pragma unroll
        for (int mt = 0; mt < 4; ++mt)
            a[mt] = Asv[kq * 128 + wm + mt * 16 + l15];
#pragma unroll
        for (int nt = 0; nt < 4; ++nt)
            b[nt] = Bsv[kq * 128 + wn + nt * 16 + l15];
#pragma unroll
        for (int mt = 0; mt < 4; ++mt)
#pragma unroll
            for (int nt = 0; nt < 4; ++nt)
                acc[mt][nt] = __builtin_amdgcn_mfma_f32_16x16x32_bf16(
                    a[mt], b[nt], acc[mt][nt], 0, 0, 0);
    }

    // Epilogue. C/D: col = lane&15, row = (lane>>4)*4 + reg  [m89/m91]
#pragma unroll
    for (int nt = 0; nt < 4; ++nt) {
        int col = col0 + wn + nt * 16 + l15;
        float bv = bias[col];
#pragma unroll
        for (int mt = 0; mt < 4; ++mt) {
#pragma unroll
            for (int r = 0; r < 4; ++r) {
                int row = row0 + wm + mt * 16 + kq * 4 + r;
                if (row >= M) continue;
                float v = acc[mt][nt][r] + bv;
                if (relu) v = fmaxf(v, 0.f);
                if (Cf) Cf[(size_t)row * N + col] = v;
                else Cb[(size_t)row * N + col] = f32_to_bf16(v);
            }
        }
    }
}

// In-place log_softmax over rows of 128; one wave per row.
__global__ __launch_bounds__(256) void logsoftmax128(float* __restrict__ out, int M) {
    int row = blockIdx.x * 4 + (threadIdx.x >> 6);
    int lane = threadIdx.x & 63;
    if (row >= M) return;
    float* p = out + (size_t)row * 128;
    float a = p[lane];
    float b = p[lane + 64];
    float m = fmaxf(a, b);
#pragma unroll
    for (int off = 32; off > 0; off >>= 1) m = fmaxf(m, __shfl_xor(m, off));
    float s = expf(a - m) + expf(b - m);
#pragma unroll
    for (int off = 32; off > 0; off >>= 1) s += __shfl_xor(s, off);
    float ls = m + logf(s);
    p[lane] = a - ls;
    p[lane + 64] = b - ls;
}

extern "C" void kernel_launch(void* const* d_in, const int* in_sizes, int n_in,
                              void* d_out, int out_size, void* d_ws, size_t ws_size,
                              hipStream_t stream) {
    const float* x    = (const float*)d_in[0];
    const int*   ei   = (const int*)d_in[1];
    const float* W1_l = (const float*)d_in[2];
    const float* b1   = (const float*)d_in[3];
    const float* W1_r = (const float*)d_in[4];
    const float* W2_l = (const float*)d_in[5];
    const float* b2   = (const float*)d_in[6];
    const float* W2_r = (const float*)d_in[7];
    const float* W3_l = (const float*)d_in[8];
    const float* b3   = (const float*)d_in[9];
    const float* W3_r = (const float*)d_in[10];
    float* out = (float*)d_out;

    const int* src = ei;
    const int* dst = ei + N_EDGES;

    // Workspace layout (bytes from base):
    char* base = (char*)d_ws;
    int* row_start = (int*)(base);                    // 50052 ints
    int* cursor    = (int*)(base + 200208);           // 50052 ints
    int* bsums     = (int*)(base + 400416);           // 512 ints
    int* csr_src   = (int*)(base + 402464);           // 400000 ints -> end 2002464
    u16* xb   = (u16*)(base + 2002464);               // 25.6M bf16
    u16* aggb = (u16*)(base + 53202464);
    u16* h1b  = (u16*)(base + 104402464);
    u16* h2b  = (u16*)(base + 155602464);
    u16* w1lT = (u16*)(base + 206802464);             // [512][512]
    u16* w1rT = (u16*)(base + 207326752);
    u16* w2lT = (u16*)(base + 207851040);
    u16* w2rT = (u16*)(base + 208375328);
    u16* w3lT = (u16*)(base + 208899616);             // [128][512]
    u16* w3rT = (u16*)(base + 209030688);             // end 209161760

    const int E = N_EDGES, M = N_NODES;
    const int nblk = (M + 255) / 256;

    // ---- CSR build ----
    zero4_kernel<<<(25154 + 255) / 256, 256, 0, stream>>>((float4*)d_ws, 25154);
    hist_kernel<<<(E + 255) / 256, 256, 0, stream>>>(dst, row_start, E);
    scan_reduce<<<nblk, 256, 0, stream>>>(row_start, bsums, M);
    scan_sums<<<1, 256, 0, stream>>>(bsums, nblk);
    scan_final<<<nblk, 256, 0, stream>>>(row_start, bsums, M);
    fill_kernel<<<(E + 255) / 256, 256, 0, stream>>>(src, dst, row_start, cursor,
                                                     csr_src, E);

    // ---- conversions ----
    convert_bf16<<<(3200000 + 255) / 256, 256, 0, stream>>>(x, xb, 3200000);
    transpose_w<<<dim3(16, 16), 256, 0, stream>>>(W1_l, w1lT, 512, 512);
    transpose_w<<<dim3(16, 16), 256, 0, stream>>>(W1_r, w1rT, 512, 512);
    transpose_w<<<dim3(16, 16), 256, 0, stream>>>(W2_l, w2lT, 512, 512);
    transpose_w<<<dim3(16, 16), 256, 0, stream>>>(W2_r, w2rT, 512, 512);
    transpose_w<<<dim3(4, 16), 256, 0, stream>>>(W3_l, w3lT, 512, 128);
    transpose_w<<<dim3(4, 16), 256, 0, stream>>>(W3_r, w3rT, 512, 128);

    const int gather_blocks = (M * 64 + 255) / 256;
    const int nStrips = (M + 127) / 128;                 // 391
    const int bigGrid = ((nStrips + 7) / 8) * 32;        // 1568 (swizzled)

    // ---- layer 1 ----
    gather_mean_bf16<<<gather_blocks, 256, 0, stream>>>(xb, row_start, csr_src, aggb, M);
    gemm_bf16<<<bigGrid, 256, 0, stream>>>(aggb, xb, w1lT, w1rT, b1,
                                           h1b, nullptr, M, 512, 1, nStrips, 4);
    // ---- layer 2 ----
    gather_mean_bf16<<<gather_blocks, 256, 0, stream>>>(h1b, row_start, csr_src, aggb, M);
    gemm_bf16<<<bigGrid, 256, 0, stream>>>(aggb, h1b, w2lT, w2rT, b2,
                                           h2b, nullptr, M, 512, 1, nStrips, 4);
    // ---- layer 3 ----
    gather_mean_bf16<<<gather_blocks, 256, 0, stream>>>(h2b, row_start, csr_src, aggb, M);
    gemm_bf16<<<nStrips, 256, 0, stream>>>(aggb, h2b, w3lT, w3rT, b3,
                                           nullptr, out, M, 128, 0, nStrips, 1);

    logsoftmax128<<<(M + 3) / 4, 256, 0, stream>>>(out, M);
}